// Round 11
// baseline (28238.248 us; speedup 1.0000x reference)
//
#include <hip/hip_runtime.h>
#include <math.h>

#define T_SEQ 4096
#define I_DIM 1024
#define H_DIM 2048
#define O_DIM 512
#define G4    8192   // 4*H
#define NBLK  512    // lstm blocks: each owns 4 h-elements, 2 blocks/CU

// ---------------------------------------------------------------------------
// Phase 1: xg[t, perm(r)] = sum_k input[t,k]*W_ih[r,k] + b_ih[r] + b_hh[r]
// perm(r): r = g*2048 + 8*q + j  ->  t*8192 + q*32 + g*8 + j
// (unchanged; lstm block B reads its 16 values at q=B>>1, j=(B&1)*4+e)
// ---------------------------------------------------------------------------
__global__ __launch_bounds__(256) void gemm_xg(
    const float* __restrict__ A, const float* __restrict__ W,
    const float* __restrict__ b_ih, const float* __restrict__ b_hh,
    float* __restrict__ xg)
{
  __shared__ __align__(16) float As[16][132];
  __shared__ __align__(16) float Bs[16][132];
  const int tid = threadIdx.x;
  const int t0 = blockIdx.y * 128;
  const int r0 = blockIdx.x * 128;
  const int tx = tid & 15, ty = tid >> 4;

  float acc[8][8];
  #pragma unroll
  for (int i = 0; i < 8; ++i)
    #pragma unroll
    for (int j = 0; j < 8; ++j) acc[i][j] = 0.f;

  for (int k0 = 0; k0 < I_DIM; k0 += 16) {
    #pragma unroll
    for (int i = 0; i < 2; ++i) {
      int lin = tid + i * 256;     // 0..511
      int row = lin >> 2;          // 0..127
      int kq  = (lin & 3) << 2;    // 0,4,8,12
      float4 va = *(const float4*)&A[(size_t)(t0 + row) * I_DIM + k0 + kq];
      As[kq+0][row] = va.x; As[kq+1][row] = va.y; As[kq+2][row] = va.z; As[kq+3][row] = va.w;
      float4 vb = *(const float4*)&W[(size_t)(r0 + row) * I_DIM + k0 + kq];
      Bs[kq+0][row] = vb.x; Bs[kq+1][row] = vb.y; Bs[kq+2][row] = vb.z; Bs[kq+3][row] = vb.w;
    }
    __syncthreads();
    #pragma unroll
    for (int kk = 0; kk < 16; ++kk) {
      float4 a0 = *(const float4*)&As[kk][ty*8];
      float4 a1 = *(const float4*)&As[kk][ty*8+4];
      float4 b0 = *(const float4*)&Bs[kk][tx*8];
      float4 b1 = *(const float4*)&Bs[kk][tx*8+4];
      float av[8] = {a0.x,a0.y,a0.z,a0.w,a1.x,a1.y,a1.z,a1.w};
      float bv[8] = {b0.x,b0.y,b0.z,b0.w,b1.x,b1.y,b1.z,b1.w};
      #pragma unroll
      for (int i = 0; i < 8; ++i)
        #pragma unroll
        for (int j = 0; j < 8; ++j)
          acc[i][j] = fmaf(av[i], bv[j], acc[i][j]);
    }
    __syncthreads();
  }

  const int rbase = r0 + tx * 8;          // multiple of 8
  const int g = rbase >> 11;              // gate 0..3
  const int q = (rbase & 2047) >> 3;      // 8-element group
  float bias[8];
  #pragma unroll
  for (int j = 0; j < 8; ++j) bias[j] = b_ih[rbase + j] + b_hh[rbase + j];
  #pragma unroll
  for (int i = 0; i < 8; ++i) {
    int t = t0 + ty * 8 + i;
    float* dst = &xg[(size_t)t * G4 + q * 32 + g * 8];
    float4 o0 = make_float4(acc[i][0]+bias[0], acc[i][1]+bias[1], acc[i][2]+bias[2], acc[i][3]+bias[3]);
    float4 o1 = make_float4(acc[i][4]+bias[4], acc[i][5]+bias[5], acc[i][6]+bias[6], acc[i][7]+bias[7]);
    *(float4*)&dst[0] = o0;
    *(float4*)&dst[4] = o1;
  }
}

__device__ __forceinline__ float sigf(float x) {
  return 1.f / (1.f + __expf(-x));
}
__device__ __forceinline__ float tanh_fast(float x) {
  return 1.f - 2.f / (__expf(2.f * x) + 1.f);   // saturates correctly
}

// ---------------------------------------------------------------------------
// Phase 2: persistent LSTM recurrence, r5 sync protocol (self-announcing
// (value,tag) pairs, NREP replicas), RESTRUCTURED geometry:
//   512 blocks x 512 threads, 2 blocks/CU (VGPR<=128 via launch_bounds +
//   ~2KB LDS -> exactly 2 co-resident; 16 waves/CU = 2x occupancy).
//   Block b owns h-elements 4b..4b+3. Per thread: 16 weight rows x 4 cols
//   = 64 floats (16 float4) -> fits the 128-VGPR budget the allocator
//   refused to exceed at 128 floats (rounds 8-10: VGPR stuck at 88).
//   Wave w's poll slice [256w,256w+256) IS its dot input: each lane's 4
//   polled h-values feed its 16 rows directly -> NO LDS h-broadcast
//   (removes 64KB/step LDS traffic + one hand-off from critical path).
//   Cross-wave combine via part[2][8][16] partials (parity double-buffer,
//   ONE barrier; race-free: waves reach step t+2's write only after the
//   t+1 barrier, which needs wave0's combine of t done).
// ---------------------------------------------------------------------------
__global__ __launch_bounds__(512, 4) void lstm_seq(
    const float* __restrict__ W_hh, const float* __restrict__ xg,
    uint2* __restrict__ hbuf, int nrep)
{
  __shared__ __align__(16) float part[2][8][16];  // [parity][wave][g*4+e]

  const int tid  = threadIdx.x;
  const int b    = blockIdx.x;      // 0..511
  const int lane = tid & 63;
  const int w    = tid >> 6;        // wave id: poll slice [256w, 256w+256)
  const int pstr = nrep << 11;      // pairs per parity
  const int myrep = b & (nrep - 1);
  const int colbase = 256 * w + 4 * lane;

  // 16 NAMED float4 weights: rows g*2048 + 4b + e, cols colbase..+3
#define WLOAD(G,E) \
  float4 w##G##E = *(const float4*)&W_hh[((size_t)(G * H_DIM + 4 * b + E)) * H_DIM + colbase];
  WLOAD(0,0) WLOAD(0,1) WLOAD(0,2) WLOAD(0,3)
  WLOAD(1,0) WLOAD(1,1) WLOAD(1,2) WLOAD(1,3)
  WLOAD(2,0) WLOAD(2,1) WLOAD(2,2) WLOAD(2,3)
  WLOAD(3,0) WLOAD(3,1) WLOAD(3,2) WLOAD(3,3)

#define PIN4(V) asm volatile("" : "+v"(V.x), "+v"(V.y), "+v"(V.z), "+v"(V.w));
  PIN4(w00) PIN4(w01) PIN4(w02) PIN4(w03)
  PIN4(w10) PIN4(w11) PIN4(w12) PIN4(w13)
  PIN4(w20) PIN4(w21) PIN4(w22) PIN4(w23)
  PIN4(w30) PIN4(w31) PIN4(w32) PIN4(w33)

  float c_reg = 0.f;          // cell state (threads 0..3 = elements 0..3)
  bool gaveup = false;

  // xg slot base for this block: q = b>>1 (8-elem group), j = (b&1)*4 + e
  const int qoff = (b >> 1) * 32 + (b & 1) * 4;
  float xg0 = 0.f, xg1 = 0.f, xg2 = 0.f, xg3 = 0.f;
  if (tid < 4) {
    const float* xp = &xg[(size_t)0 * G4 + qoff + tid];
    xg0 = xp[0]; xg1 = xp[8]; xg2 = xp[16]; xg3 = xp[24];
  }

  for (int t = 0; t < T_SEQ; ++t) {
    const int par = t & 1;
    const unsigned tag = (unsigned)t;
    const uint2* a0 = hbuf + par * pstr + (myrep << 11) + colbase;

    // 1) poll my 4 pairs until all tags == t (the poll IS the h read)
    uint4 f0, f1;
    int tries = 0;
    for (;;) {
      asm volatile("global_load_dwordx4 %0, %2, off sc0 sc1\n\t"
                   "global_load_dwordx4 %1, %3, off sc0 sc1\n\t"
                   "s_waitcnt vmcnt(0)"
                   : "=&v"(f0), "=&v"(f1)
                   : "v"(a0), "v"(a0 + 2)
                   : "memory");
      bool ok = (f0.y == tag) & (f0.w == tag) & (f1.y == tag) & (f1.w == tag);
      if (__all(ok) || gaveup) break;
      if (++tries > (1 << 18)) { gaveup = true; break; }
    }
    const float hx = __uint_as_float(f0.x);
    const float hy = __uint_as_float(f0.z);
    const float hz = __uint_as_float(f1.x);
    const float hw = __uint_as_float(f1.z);

    // prefetch xg for t+1 (off the critical path)
    float nx0 = 0.f, nx1 = 0.f, nx2 = 0.f, nx3 = 0.f;
    if (tid < 4 && t + 1 < T_SEQ) {
      const float* xp = &xg[(size_t)(t + 1) * G4 + qoff + tid];
      nx0 = xp[0]; nx1 = xp[8]; nx2 = xp[16]; nx3 = xp[24];
    }

    // 2) 16 dots (4 cols each) from registers
#define SDOT(G,E) \
    float s##G##E = w##G##E.x * hx; \
    s##G##E = fmaf(w##G##E.y, hy, s##G##E); \
    s##G##E = fmaf(w##G##E.z, hz, s##G##E); \
    s##G##E = fmaf(w##G##E.w, hw, s##G##E);
    SDOT(0,0) SDOT(0,1) SDOT(0,2) SDOT(0,3)
    SDOT(1,0) SDOT(1,1) SDOT(1,2) SDOT(1,3)
    SDOT(2,0) SDOT(2,1) SDOT(2,2) SDOT(2,3)
    SDOT(3,0) SDOT(3,1) SDOT(3,2) SDOT(3,3)

    // 3) butterfly-reduce 16 values across 64 lanes
#define SHF(G,E) s##G##E += __shfl_xor(s##G##E, sh, 64);
    #pragma unroll
    for (int sh = 32; sh >= 1; sh >>= 1) {
      SHF(0,0) SHF(0,1) SHF(0,2) SHF(0,3)
      SHF(1,0) SHF(1,1) SHF(1,2) SHF(1,3)
      SHF(2,0) SHF(2,1) SHF(2,2) SHF(2,3)
      SHF(3,0) SHF(3,1) SHF(3,2) SHF(3,3)
    }

    // 4) lane 0 of each wave publishes 16 partials (parity dbuf)
    if (lane == 0) {
      *(float4*)&part[par][w][ 0] = make_float4(s00, s01, s02, s03);
      *(float4*)&part[par][w][ 4] = make_float4(s10, s11, s12, s13);
      *(float4*)&part[par][w][ 8] = make_float4(s20, s21, s22, s23);
      *(float4*)&part[par][w][12] = make_float4(s30, s31, s32, s33);
    }
    __syncthreads();   // the ONE barrier per step

    // 5) threads 0..3 (element e=tid): combine 8 waves, gates, c, store
    if (tid < 4) {
      float p0 = 0.f, p1 = 0.f, p2 = 0.f, p3 = 0.f;
      #pragma unroll
      for (int ww = 0; ww < 8; ++ww) {
        p0 += part[par][ww][ 0 + tid];
        p1 += part[par][ww][ 4 + tid];
        p2 += part[par][ww][ 8 + tid];
        p3 += part[par][ww][12 + tid];
      }
      float iv = sigf(p0 + xg0);
      float fv = sigf(p1 + xg1);
      float gv = tanh_fast(p2 + xg2);
      float ov = sigf(p3 + xg3);
      c_reg = fv * c_reg + iv * gv;
      float hv = ov * tanh_fast(c_reg);
      uint2 pv;
      pv.x = __float_as_uint(hv);
      pv.y = (unsigned)(t + 1);
      uint2* dst = hbuf + ((t + 1) & 1) * pstr + 4 * b + tid;
      for (int r = 0; r < nrep; ++r) {
        asm volatile("global_store_dwordx2 %0, %1, off sc0 sc1"
                     :: "v"(dst), "v"(pv) : "memory");
        dst += 2048;
      }
    }

    xg0 = nx0; xg1 = nx1; xg2 = nx2; xg3 = nx3;
  }
}

// ---------------------------------------------------------------------------
// Phase 3: out[o] = h_last . W_lin[o,:] + b_lin[o]. One wave per output.
// h_last = values of replica-0 pairs at parity 0 (step 4095 writes par 0).
// ---------------------------------------------------------------------------
__global__ __launch_bounds__(256) void proj_out(
    const float* __restrict__ W_lin, const float* __restrict__ b_lin,
    const uint2* __restrict__ hpairs, float* __restrict__ out)
{
  const int tid = threadIdx.x;
  const int lane = tid & 63;
  const int w4 = tid >> 6;
  const int o = blockIdx.x * 4 + w4;
  const float* wr = &W_lin[(size_t)o * H_DIM + 4 * lane];
  float s = 0.f;
  #pragma unroll
  for (int k = 0; k < 8; ++k) {
    float4 wv = *(const float4*)&wr[256 * k];
    uint4 p0 = *(const uint4*)&hpairs[4 * lane + 256 * k];       // v,t,v,t
    uint4 p1 = *(const uint4*)&hpairs[4 * lane + 256 * k + 2];   // v,t,v,t
    s = fmaf(wv.x, __uint_as_float(p0.x), s);
    s = fmaf(wv.y, __uint_as_float(p0.z), s);
    s = fmaf(wv.z, __uint_as_float(p1.x), s);
    s = fmaf(wv.w, __uint_as_float(p1.z), s);
  }
  #pragma unroll
  for (int sh = 32; sh >= 1; sh >>= 1) s += __shfl_xor(s, sh, 64);
  if (lane == 0) out[o] = s + b_lin[o];
}

// ---------------------------------------------------------------------------
extern "C" void kernel_launch(void* const* d_in, const int* in_sizes, int n_in,
                              void* d_out, int out_size, void* d_ws, size_t ws_size,
                              hipStream_t stream)
{
  const float* input = (const float*)d_in[0];
  const float* W_ih  = (const float*)d_in[1];
  const float* W_hh  = (const float*)d_in[2];
  const float* b_ih  = (const float*)d_in[3];
  const float* b_hh  = (const float*)d_in[4];
  const float* W_lin = (const float*)d_in[5];
  const float* b_lin = (const float*)d_in[6];
  float* out = (float*)d_out;

  char* ws = (char*)d_ws;
  const size_t XG_BYTES = (size_t)T_SEQ * G4 * sizeof(float);   // 128 MB
  float* xg   = (float*)ws;
  uint2* hbuf = (uint2*)(ws + XG_BYTES);

  // 8 replicas if the workspace allows (2 parities x 8 replicas x 2048 pairs
  // x 8B = 256KB), else fall back to the single-copy layout.
  const size_t HB8 = 2ull * 8 * H_DIM * sizeof(uint2);
  int nrep = (ws_size >= XG_BYTES + HB8) ? 8 : 1;
  const size_t HB_BYTES = 2ull * nrep * H_DIM * sizeof(uint2);

  // zero all pair buffers: h_0 = 0 with tag 0 (= step-0 poll target)
  (void)hipMemsetAsync(ws + XG_BYTES, 0, HB_BYTES, stream);

  gemm_xg<<<dim3(64, 32), 256, 0, stream>>>(input, W_ih, b_ih, b_hh, xg);
  lstm_seq<<<NBLK, 512, 0, stream>>>(W_hh, xg, hbuf, nrep);
  proj_out<<<128, 256, 0, stream>>>(W_lin, b_lin, hbuf, out);
}

// Round 12
// 15028.604 us; speedup vs baseline: 1.8790x; 1.8790x over previous
//
#include <hip/hip_runtime.h>
#include <math.h>

#define T_SEQ 4096
#define I_DIM 1024
#define H_DIM 2048
#define O_DIM 512
#define G4    8192   // 4*H

// ---------------------------------------------------------------------------
// Phase 1: xg[t, perm(r)] = sum_k input[t,k]*W_ih[r,k] + b_ih[r] + b_hh[r]
// perm(r): r = g*2048 + 8*q + j  ->  t*8192 + q*32 + g*8 + j
// ---------------------------------------------------------------------------
__global__ __launch_bounds__(256) void gemm_xg(
    const float* __restrict__ A, const float* __restrict__ W,
    const float* __restrict__ b_ih, const float* __restrict__ b_hh,
    float* __restrict__ xg)
{
  __shared__ __align__(16) float As[16][132];
  __shared__ __align__(16) float Bs[16][132];
  const int tid = threadIdx.x;
  const int t0 = blockIdx.y * 128;
  const int r0 = blockIdx.x * 128;
  const int tx = tid & 15, ty = tid >> 4;

  float acc[8][8];
  #pragma unroll
  for (int i = 0; i < 8; ++i)
    #pragma unroll
    for (int j = 0; j < 8; ++j) acc[i][j] = 0.f;

  for (int k0 = 0; k0 < I_DIM; k0 += 16) {
    #pragma unroll
    for (int i = 0; i < 2; ++i) {
      int lin = tid + i * 256;     // 0..511
      int row = lin >> 2;          // 0..127
      int kq  = (lin & 3) << 2;    // 0,4,8,12
      float4 va = *(const float4*)&A[(size_t)(t0 + row) * I_DIM + k0 + kq];
      As[kq+0][row] = va.x; As[kq+1][row] = va.y; As[kq+2][row] = va.z; As[kq+3][row] = va.w;
      float4 vb = *(const float4*)&W[(size_t)(r0 + row) * I_DIM + k0 + kq];
      Bs[kq+0][row] = vb.x; Bs[kq+1][row] = vb.y; Bs[kq+2][row] = vb.z; Bs[kq+3][row] = vb.w;
    }
    __syncthreads();
    #pragma unroll
    for (int kk = 0; kk < 16; ++kk) {
      float4 a0 = *(const float4*)&As[kk][ty*8];
      float4 a1 = *(const float4*)&As[kk][ty*8+4];
      float4 b0 = *(const float4*)&Bs[kk][tx*8];
      float4 b1 = *(const float4*)&Bs[kk][tx*8+4];
      float av[8] = {a0.x,a0.y,a0.z,a0.w,a1.x,a1.y,a1.z,a1.w};
      float bv[8] = {b0.x,b0.y,b0.z,b0.w,b1.x,b1.y,b1.z,b1.w};
      #pragma unroll
      for (int i = 0; i < 8; ++i)
        #pragma unroll
        for (int j = 0; j < 8; ++j)
          acc[i][j] = fmaf(av[i], bv[j], acc[i][j]);
    }
    __syncthreads();
  }

  const int rbase = r0 + tx * 8;
  const int g = rbase >> 11;
  const int q = (rbase & 2047) >> 3;
  float bias[8];
  #pragma unroll
  for (int j = 0; j < 8; ++j) bias[j] = b_ih[rbase + j] + b_hh[rbase + j];
  #pragma unroll
  for (int i = 0; i < 8; ++i) {
    int t = t0 + ty * 8 + i;
    float* dst = &xg[(size_t)t * G4 + q * 32 + g * 8];
    float4 o0 = make_float4(acc[i][0]+bias[0], acc[i][1]+bias[1], acc[i][2]+bias[2], acc[i][3]+bias[3]);
    float4 o1 = make_float4(acc[i][4]+bias[4], acc[i][5]+bias[5], acc[i][6]+bias[6], acc[i][7]+bias[7]);
    *(float4*)&dst[0] = o0;
    *(float4*)&dst[4] = o1;
  }
}

__device__ __forceinline__ float sigf(float x) {
  return 1.f / (1.f + __expf(-x));
}
__device__ __forceinline__ float tanh_fast(float x) {
  return 1.f - 2.f / (__expf(2.f * x) + 1.f);
}

// ---------------------------------------------------------------------------
// pack_whh: W_hh fp32 -> packed bf16 pairs (RNE). Wp[r][cp] = bf16(W[r][2cp])
// | bf16(W[r][2cp+1])<<16. 8.4M uints, one-time ~20us.
// ---------------------------------------------------------------------------
__device__ __forceinline__ unsigned bf16rne(float f) {
  unsigned u = __float_as_uint(f);
  return (u + 0x7fffu + ((u >> 16) & 1u)) >> 16;
}
__global__ __launch_bounds__(256) void pack_whh(
    const float* __restrict__ W, unsigned* __restrict__ Wp)
{
  size_t i = (size_t)blockIdx.x * 256 + threadIdx.x;   // pair index
  float2 v = *(const float2*)&W[2 * i];
  Wp[i] = bf16rne(v.x) | (bf16rne(v.y) << 16);
}

// ---------------------------------------------------------------------------
// Phase 2 (primary): r5 geometry+sync, weights as PACKED BF16 in registers.
// Rounds 8-11 lesson: fp32 weights (128 VGPRs) always lose the register-
// allocator fight (VGPR stuck at 88/60, weights re-streamed from cache
// every step ~24 TB/s = the 2.6us/step floor). bf16 halves the footprint:
// 64 packed uint32 -> demand ~115 regs fits ANY plausible cap (128/256).
// Unpack = 1 shift or mask per weight (bf16->fp32 is a 16-bit shift),
// ~256 VALU inst/step = 0.2us, off the memory system entirely.
// Sync: r5 self-announcing (value,tag) pairs, NREP replicas, one barrier.
// ---------------------------------------------------------------------------
__global__ __launch_bounds__(512, 2) void lstm_seq_bf16(
    const unsigned* __restrict__ Wp, const float* __restrict__ xg,
    uint2* __restrict__ hbuf, int nrep)
{
  __shared__ __align__(16) float smem[21000];  // 84 KB -> 1 block/CU
  float* hsh = smem;                           // 2 x 2048 broadcast buffers

  const int tid  = threadIdx.x;
  const int b    = blockIdx.x;     // 0..255
  const int lane = tid & 63;
  const int w    = tid >> 6;       // wave id = h element index within block
  const int pstr = nrep << 11;
  const int myrep = b & (nrep - 1);

  // Packed weights: row g*2048 + 8b + w, pair-cols 2*lane + 128*k (k=0..7).
  // 32 NAMED uint2 (64 VGPRs), pinned so they can't be re-materialized.
#define WL(G,K) uint2 u##G##K = *(const uint2*)&Wp[((size_t)(G * H_DIM + 8 * b + w)) * (H_DIM/2) + 2 * lane + 128 * K];
  WL(0,0) WL(0,1) WL(0,2) WL(0,3) WL(0,4) WL(0,5) WL(0,6) WL(0,7)
  WL(1,0) WL(1,1) WL(1,2) WL(1,3) WL(1,4) WL(1,5) WL(1,6) WL(1,7)
  WL(2,0) WL(2,1) WL(2,2) WL(2,3) WL(2,4) WL(2,5) WL(2,6) WL(2,7)
  WL(3,0) WL(3,1) WL(3,2) WL(3,3) WL(3,4) WL(3,5) WL(3,6) WL(3,7)
#define PINU(G,K) asm volatile("" : "+v"(u##G##K.x), "+v"(u##G##K.y));
  PINU(0,0) PINU(0,1) PINU(0,2) PINU(0,3) PINU(0,4) PINU(0,5) PINU(0,6) PINU(0,7)
  PINU(1,0) PINU(1,1) PINU(1,2) PINU(1,3) PINU(1,4) PINU(1,5) PINU(1,6) PINU(1,7)
  PINU(2,0) PINU(2,1) PINU(2,2) PINU(2,3) PINU(2,4) PINU(2,5) PINU(2,6) PINU(2,7)
  PINU(3,0) PINU(3,1) PINU(3,2) PINU(3,3) PINU(3,4) PINU(3,5) PINU(3,6) PINU(3,7)

  float c_reg = 0.f;
  bool gaveup = false;

  const float* xp0 = &xg[(size_t)0 * G4 + b * 32 + w];
  float xgi = xp0[0], xgf = xp0[8], xgg = xp0[16], xgo = xp0[24];

  for (int t = 0; t < T_SEQ; ++t) {
    const uint2* hb = hbuf + (t & 1) * pstr + (myrep << 11);
    const unsigned tag = (unsigned)t;

    // 1) poll my 4 pairs until all tags == t (the poll IS the h read)
    const uint2* a0 = hb + 256 * w + 4 * lane;
    uint4 f0, f1;
    int tries = 0;
    for (;;) {
      asm volatile("global_load_dwordx4 %0, %2, off sc0 sc1\n\t"
                   "global_load_dwordx4 %1, %3, off sc0 sc1\n\t"
                   "s_waitcnt vmcnt(0)"
                   : "=&v"(f0), "=&v"(f1)
                   : "v"(a0), "v"(a0 + 2)
                   : "memory");
      bool ok = (f0.y == tag) & (f0.w == tag) & (f1.y == tag) & (f1.w == tag);
      if (__all(ok) || gaveup) break;
      if (++tries > (1 << 17)) { gaveup = true; break; }
    }

    // 2) broadcast values into this step's LDS buffer
    float* hd = hsh + ((t & 1) << 11);
    float4 hv4 = make_float4(__uint_as_float(f0.x), __uint_as_float(f0.z),
                             __uint_as_float(f1.x), __uint_as_float(f1.z));
    *(float4*)&hd[256 * w + 4 * lane] = hv4;

    // prefetch xg for t+1 (off the critical path)
    float nxi = 0.f, nxf = 0.f, nxg = 0.f, nxo = 0.f;
    if (t + 1 < T_SEQ) {
      const float* xp = &xg[(size_t)(t + 1) * G4 + b * 32 + w];
      nxi = xp[0]; nxf = xp[8]; nxg = xp[16]; nxo = xp[24];
    }

    __syncthreads();   // the ONE barrier per step

    // 3) dot: 4 gate rows x 32 cols/lane; unpack bf16 inline (shift/mask)
    float s0 = 0.f, s1 = 0.f, s2 = 0.f, s3 = 0.f;
#define DOTGK(S,G,K) { \
    float wa = __uint_as_float(u##G##K.x << 16); \
    float wb = __uint_as_float(u##G##K.x & 0xffff0000u); \
    float wc = __uint_as_float(u##G##K.y << 16); \
    float wd = __uint_as_float(u##G##K.y & 0xffff0000u); \
    S = fmaf(wa, hv.x, S); S = fmaf(wb, hv.y, S); \
    S = fmaf(wc, hv.z, S); S = fmaf(wd, hv.w, S); }
#define DOTK(K) { \
    float4 hv = *(const float4*)&hd[4 * lane + 256 * K]; \
    DOTGK(s0,0,K) DOTGK(s1,1,K) DOTGK(s2,2,K) DOTGK(s3,3,K) }
    DOTK(0) DOTK(1) DOTK(2) DOTK(3) DOTK(4) DOTK(5) DOTK(6) DOTK(7)

    // butterfly reduce 4 values across 64 lanes
    #pragma unroll
    for (int sh = 32; sh >= 1; sh >>= 1) {
      s0 += __shfl_xor(s0, sh, 64);
      s1 += __shfl_xor(s1, sh, 64);
      s2 += __shfl_xor(s2, sh, 64);
      s3 += __shfl_xor(s3, sh, 64);
    }

    // 4) lane 0: gate math + nrep packed (value, tag) stores
    if (lane == 0) {
      float iv = sigf(s0 + xgi);
      float fv = sigf(s1 + xgf);
      float gv = tanh_fast(s2 + xgg);
      float ov = sigf(s3 + xgo);
      c_reg = fv * c_reg + iv * gv;
      float hv = ov * tanh_fast(c_reg);
      uint2 pv;
      pv.x = __float_as_uint(hv);
      pv.y = (unsigned)(t + 1);
      uint2* dst = hbuf + ((t + 1) & 1) * pstr + 8 * b + w;
      for (int r = 0; r < nrep; ++r) {
        asm volatile("global_store_dwordx2 %0, %1, off sc0 sc1"
                     :: "v"(dst), "v"(pv) : "memory");
        dst += 2048;
      }
    }

    xgi = nxi; xgf = nxf; xgg = nxg; xgo = nxo;
  }
}

// ---------------------------------------------------------------------------
// Phase 2 (fallback, ws too small for Wp): round-5 fp32 kernel, verified
// 10.8 ms. Weights stream from cache each step.
// ---------------------------------------------------------------------------
__global__ __launch_bounds__(512, 2) void lstm_seq_f32(
    const float* __restrict__ W_hh, const float* __restrict__ xg,
    uint2* __restrict__ hbuf, int nrep)
{
  __shared__ __align__(16) float smem[21000];
  float* hsh = smem;

  const int tid  = threadIdx.x;
  const int b    = blockIdx.x;
  const int lane = tid & 63;
  const int w    = tid >> 6;
  const int pstr = nrep << 11;
  const int myrep = b & (nrep - 1);

  float4 wt[4][8];
  #pragma unroll
  for (int g = 0; g < 4; ++g) {
    const float* wr = &W_hh[(size_t)(g * H_DIM + 8 * b + w) * H_DIM + 4 * lane];
    #pragma unroll
    for (int k = 0; k < 8; ++k) wt[g][k] = *(const float4*)&wr[256 * k];
  }

  float c_reg = 0.f;
  bool gaveup = false;

  const float* xp0 = &xg[(size_t)0 * G4 + b * 32 + w];
  float xgi = xp0[0], xgf = xp0[8], xgg = xp0[16], xgo = xp0[24];

  for (int t = 0; t < T_SEQ; ++t) {
    const uint2* hb = hbuf + (t & 1) * pstr + (myrep << 11);
    const unsigned tag = (unsigned)t;

    const uint2* a0 = hb + 256 * w + 4 * lane;
    uint4 f0, f1;
    int tries = 0;
    for (;;) {
      asm volatile("global_load_dwordx4 %0, %2, off sc0 sc1\n\t"
                   "global_load_dwordx4 %1, %3, off sc0 sc1\n\t"
                   "s_waitcnt vmcnt(0)"
                   : "=&v"(f0), "=&v"(f1)
                   : "v"(a0), "v"(a0 + 2)
                   : "memory");
      bool ok = (f0.y == tag) & (f0.w == tag) & (f1.y == tag) & (f1.w == tag);
      if (__all(ok) || gaveup) break;
      if (++tries > (1 << 17)) { gaveup = true; break; }
    }

    float* hd = hsh + ((t & 1) << 11);
    float4 hv4 = make_float4(__uint_as_float(f0.x), __uint_as_float(f0.z),
                             __uint_as_float(f1.x), __uint_as_float(f1.z));
    *(float4*)&hd[256 * w + 4 * lane] = hv4;

    float nxi = 0.f, nxf = 0.f, nxg = 0.f, nxo = 0.f;
    if (t + 1 < T_SEQ) {
      const float* xp = &xg[(size_t)(t + 1) * G4 + b * 32 + w];
      nxi = xp[0]; nxf = xp[8]; nxg = xp[16]; nxo = xp[24];
    }

    __syncthreads();

    float s0 = 0.f, s1 = 0.f, s2 = 0.f, s3 = 0.f;
    #pragma unroll
    for (int k = 0; k < 8; ++k) {
      float4 hv = *(const float4*)&hd[4 * lane + 256 * k];
      s0 = fmaf(wt[0][k].x, hv.x, s0); s0 = fmaf(wt[0][k].y, hv.y, s0);
      s0 = fmaf(wt[0][k].z, hv.z, s0); s0 = fmaf(wt[0][k].w, hv.w, s0);
      s1 = fmaf(wt[1][k].x, hv.x, s1); s1 = fmaf(wt[1][k].y, hv.y, s1);
      s1 = fmaf(wt[1][k].z, hv.z, s1); s1 = fmaf(wt[1][k].w, hv.w, s1);
      s2 = fmaf(wt[2][k].x, hv.x, s2); s2 = fmaf(wt[2][k].y, hv.y, s2);
      s2 = fmaf(wt[2][k].z, hv.z, s2); s2 = fmaf(wt[2][k].w, hv.w, s2);
      s3 = fmaf(wt[3][k].x, hv.x, s3); s3 = fmaf(wt[3][k].y, hv.y, s3);
      s3 = fmaf(wt[3][k].z, hv.z, s3); s3 = fmaf(wt[3][k].w, hv.w, s3);
    }

    #pragma unroll
    for (int sh = 32; sh >= 1; sh >>= 1) {
      s0 += __shfl_xor(s0, sh, 64);
      s1 += __shfl_xor(s1, sh, 64);
      s2 += __shfl_xor(s2, sh, 64);
      s3 += __shfl_xor(s3, sh, 64);
    }

    if (lane == 0) {
      float iv = sigf(s0 + xgi);
      float fv = sigf(s1 + xgf);
      float gv = tanh_fast(s2 + xgg);
      float ov = sigf(s3 + xgo);
      c_reg = fv * c_reg + iv * gv;
      float hv = ov * tanh_fast(c_reg);
      uint2 pv;
      pv.x = __float_as_uint(hv);
      pv.y = (unsigned)(t + 1);
      uint2* dst = hbuf + ((t + 1) & 1) * pstr + 8 * b + w;
      for (int r = 0; r < nrep; ++r) {
        asm volatile("global_store_dwordx2 %0, %1, off sc0 sc1"
                     :: "v"(dst), "v"(pv) : "memory");
        dst += 2048;
      }
    }

    xgi = nxi; xgf = nxf; xgg = nxg; xgo = nxo;
  }
}

// ---------------------------------------------------------------------------
// Phase 3: out[o] = h_last . W_lin[o,:] + b_lin[o]. One wave per output.
// ---------------------------------------------------------------------------
__global__ __launch_bounds__(256) void proj_out(
    const float* __restrict__ W_lin, const float* __restrict__ b_lin,
    const uint2* __restrict__ hpairs, float* __restrict__ out)
{
  const int tid = threadIdx.x;
  const int lane = tid & 63;
  const int w4 = tid >> 6;
  const int o = blockIdx.x * 4 + w4;
  const float* wr = &W_lin[(size_t)o * H_DIM + 4 * lane];
  float s = 0.f;
  #pragma unroll
  for (int k = 0; k < 8; ++k) {
    float4 wv = *(const float4*)&wr[256 * k];
    uint4 p0 = *(const uint4*)&hpairs[4 * lane + 256 * k];
    uint4 p1 = *(const uint4*)&hpairs[4 * lane + 256 * k + 2];
    s = fmaf(wv.x, __uint_as_float(p0.x), s);
    s = fmaf(wv.y, __uint_as_float(p0.z), s);
    s = fmaf(wv.z, __uint_as_float(p1.x), s);
    s = fmaf(wv.w, __uint_as_float(p1.z), s);
  }
  #pragma unroll
  for (int sh = 32; sh >= 1; sh >>= 1) s += __shfl_xor(s, sh, 64);
  if (lane == 0) out[o] = s + b_lin[o];
}

// ---------------------------------------------------------------------------
extern "C" void kernel_launch(void* const* d_in, const int* in_sizes, int n_in,
                              void* d_out, int out_size, void* d_ws, size_t ws_size,
                              hipStream_t stream)
{
  const float* input = (const float*)d_in[0];
  const float* W_ih  = (const float*)d_in[1];
  const float* W_hh  = (const float*)d_in[2];
  const float* b_ih  = (const float*)d_in[3];
  const float* b_hh  = (const float*)d_in[4];
  const float* W_lin = (const float*)d_in[5];
  const float* b_lin = (const float*)d_in[6];
  float* out = (float*)d_out;

  char* ws = (char*)d_ws;
  const size_t XG_BYTES = (size_t)T_SEQ * G4 * sizeof(float);          // 128 MB
  const size_t HB8      = 2ull * 8 * H_DIM * sizeof(uint2);            // 256 KB
  const size_t WP_BYTES = (size_t)G4 * (H_DIM / 2) * sizeof(unsigned); // 32 MB
  float* xg   = (float*)ws;
  uint2* hbuf = (uint2*)(ws + XG_BYTES);

  int nrep = (ws_size >= XG_BYTES + HB8) ? 8 : 1;
  const size_t HB_BYTES = 2ull * nrep * H_DIM * sizeof(uint2);

  (void)hipMemsetAsync(ws + XG_BYTES, 0, HB_BYTES, stream);

  gemm_xg<<<dim3(64, 32), 256, 0, stream>>>(input, W_ih, b_ih, b_hh, xg);

  if (nrep == 8 && ws_size >= XG_BYTES + HB8 + WP_BYTES) {
    unsigned* Wp = (unsigned*)(ws + XG_BYTES + HB8);
    pack_whh<<<(int)((size_t)G4 * (H_DIM / 2) / 256), 256, 0, stream>>>(W_hh, Wp);
    lstm_seq_bf16<<<256, 512, 0, stream>>>(Wp, xg, hbuf, nrep);
  } else {
    lstm_seq_f32<<<256, 512, 0, stream>>>(W_hh, xg, hbuf, nrep);
  }

  proj_out<<<128, 256, 0, stream>>>(W_lin, b_lin, hbuf, out);
}